// Round 1
// baseline (365.707 us; speedup 1.0000x reference)
//
#include <hip/hip_runtime.h>
#include <hip/hip_bf16.h>

typedef short bf16x8 __attribute__((ext_vector_type(8)));   // 8 bf16 in 4 VGPRs
typedef float f32x4 __attribute__((ext_vector_type(4)));

#define NB 8192
#define ND 256
#define INV_T 20.0f      // 1/TEMPERATURE
#define TEMP 0.05f
#define LAMBDA 0.7f

// ---------------- Kernel 1: row L2-normalize, write bf16 copy ----------------
__global__ __launch_bounds__(256) void normalize_kernel(
    const float* __restrict__ feat, unsigned short* __restrict__ fb) {
    const int row = blockIdx.x;
    const int tid = threadIdx.x;           // 256 threads = 1 per column
    float v = feat[row * ND + tid];
    float ss = v * v;
    // reduce within wave (64 lanes)
    #pragma unroll
    for (int off = 32; off > 0; off >>= 1) ss += __shfl_xor(ss, off);
    __shared__ float part[4];
    if ((tid & 63) == 0) part[tid >> 6] = ss;
    __syncthreads();
    float tot = part[0] + part[1] + part[2] + part[3];
    float inv = rsqrtf(tot);
    float nv = v * inv;
    __hip_bfloat16 h = __float2bfloat16(nv);
    fb[row * ND + tid] = *reinterpret_cast<unsigned short*>(&h);
}

// ---------------- Kernel 2: fused sim tile + epilogue reductions ----------------
// grid (64,64); block 256 = 4 waves; each block computes 128x128 tile of sim,
// each wave a 64x64 sub-tile as 4x4 fragments of 16x16x32 bf16 MFMA.
__global__ __launch_bounds__(256) void sim_kernel(
    const unsigned short* __restrict__ fb, const int* __restrict__ labels,
    float* __restrict__ denom, float* __restrict__ possum,
    float* __restrict__ hsum, float* __restrict__ nposf,
    float* __restrict__ nhighf) {
    const int I0 = blockIdx.y * 128;
    const int J0 = blockIdx.x * 128;
    const int tid  = threadIdx.x;
    const int wave = tid >> 6;
    const int lane = tid & 63;
    const int wy = wave >> 1, wx = wave & 1;
    const int rbase = I0 + 64 * wy;        // this wave's A-row base
    const int cbase = J0 + 64 * wx;        // this wave's B-row (col) base
    const int l15  = lane & 15;
    const int quad = lane >> 4;

    f32x4 zero4 = {0.f, 0.f, 0.f, 0.f};
    f32x4 acc[4][4];
    #pragma unroll
    for (int fy = 0; fy < 4; ++fy)
        #pragma unroll
        for (int fx = 0; fx < 4; ++fx) acc[fy][fx] = zero4;

    // lane's base pointers: A-frag = f[rbase+l15][quad*8 + k0 + j], same shape for B
    const unsigned short* arow = fb + (size_t)(rbase + l15) * ND + quad * 8;
    const unsigned short* brow = fb + (size_t)(cbase + l15) * ND + quad * 8;

    #pragma unroll
    for (int k0 = 0; k0 < ND; k0 += 32) {
        bf16x8 a[4], b[4];
        #pragma unroll
        for (int f = 0; f < 4; ++f) {
            a[f] = *reinterpret_cast<const bf16x8*>(arow + (size_t)(16 * f) * ND + k0);
            b[f] = *reinterpret_cast<const bf16x8*>(brow + (size_t)(16 * f) * ND + k0);
        }
        #pragma unroll
        for (int fy = 0; fy < 4; ++fy)
            #pragma unroll
            for (int fx = 0; fx < 4; ++fx)
                acc[fy][fx] = __builtin_amdgcn_mfma_f32_16x16x32_bf16(
                    a[fy], b[fx], acc[fy][fx], 0, 0, 0);
    }

    // labels for this lane's columns (4 of them, one per fx)
    int lcol[4];
    #pragma unroll
    for (int fx = 0; fx < 4; ++fx) lcol[fx] = labels[cbase + 16 * fx + l15];

    // Epilogue: C/D layout col=lane&15, row=quad*4+reg (m89/m91-verified)
    #pragma unroll
    for (int fy = 0; fy < 4; ++fy) {
        #pragma unroll
        for (int r = 0; r < 4; ++r) {
            const int row  = rbase + 16 * fy + quad * 4 + r;
            const int lrow = labels[row];
            float d = 0.f, ps = 0.f, hs = 0.f, np = 0.f, nh = 0.f;
            #pragma unroll
            for (int fx = 0; fx < 4; ++fx) {
                const int col = cbase + 16 * fx + l15;
                float sim = acc[fy][fx][r] * INV_T;
                if (col != row) {
                    float e = __expf(sim);
                    d += e;
                    if (lcol[fx] == lrow) {
                        np += 1.f;
                        ps += sim;
                        if (sim * TEMP > LAMBDA) { hs += e; nh += 1.f; }
                    }
                }
            }
            // reduce across the 16 lanes sharing this row (xor masks stay <16)
            #pragma unroll
            for (int off = 8; off > 0; off >>= 1) {
                d  += __shfl_xor(d, off);
                ps += __shfl_xor(ps, off);
                hs += __shfl_xor(hs, off);
                np += __shfl_xor(np, off);
                nh += __shfl_xor(nh, off);
            }
            if (l15 == 0) {
                atomicAdd(&denom[row], d);
                if (np > 0.f) {
                    atomicAdd(&possum[row], ps);
                    atomicAdd(&nposf[row], np);
                }
                if (nh > 0.f) {
                    atomicAdd(&hsum[row], hs);
                    atomicAdd(&nhighf[row], nh);
                }
            }
        }
    }
}

// ---------------- Kernel 3: scalar finalize ----------------
__global__ __launch_bounds__(256) void finalize_kernel(
    const float* __restrict__ denom, const float* __restrict__ possum,
    const float* __restrict__ hsum, const float* __restrict__ nposf,
    const float* __restrict__ nhighf, float* __restrict__ out) {
    const int tid = threadIdx.x;
    float scl_num = 0.f, npos_tot = 0.f, rl = 0.f, nh_tot = 0.f;
    const float self_term = __expf(INV_T);   // exp(1/T)
    for (int i = tid; i < NB; i += 256) {
        float np = nposf[i];
        scl_num += np * logf(denom[i] + 1e-8f) - possum[i];
        npos_tot += np;
        float h = hsum[i];
        if (h > 0.f) rl += logf(h + self_term);
        nh_tot += nhighf[i];
    }
    // wave reduce then LDS across 4 waves
    #pragma unroll
    for (int off = 32; off > 0; off >>= 1) {
        scl_num  += __shfl_xor(scl_num, off);
        npos_tot += __shfl_xor(npos_tot, off);
        rl       += __shfl_xor(rl, off);
        nh_tot   += __shfl_xor(nh_tot, off);
    }
    __shared__ float part[4][4];
    if ((tid & 63) == 0) {
        int w = tid >> 6;
        part[w][0] = scl_num; part[w][1] = npos_tot;
        part[w][2] = rl;      part[w][3] = nh_tot;
    }
    __syncthreads();
    if (tid == 0) {
        float sn = part[0][0] + part[1][0] + part[2][0] + part[3][0];
        float nt = part[0][1] + part[1][1] + part[2][1] + part[3][1];
        float rs = part[0][2] + part[1][2] + part[2][2] + part[3][2];
        float nh = part[0][3] + part[1][3] + part[2][3] + part[3][3];
        float scl   = (nt > 0.f) ? sn / nt : 0.f;
        float relax = (nh > 0.f) ? rs / nh : 0.f;
        out[0] = scl + relax;
    }
}

extern "C" void kernel_launch(void* const* d_in, const int* in_sizes, int n_in,
                              void* d_out, int out_size, void* d_ws, size_t ws_size,
                              hipStream_t stream) {
    const float* feat  = (const float*)d_in[0];
    const int* labels  = (const int*)d_in[1];
    float* out = (float*)d_out;

    char* ws = (char*)d_ws;
    unsigned short* fb = (unsigned short*)ws;                 // 8192*256*2 = 4 MB
    float* denom  = (float*)(ws + (size_t)NB * ND * sizeof(unsigned short));
    float* possum = denom  + NB;
    float* hsum   = possum + NB;
    float* nposf  = hsum   + NB;
    float* nhighf = nposf  + NB;

    hipMemsetAsync(denom, 0, (size_t)5 * NB * sizeof(float), stream);
    normalize_kernel<<<NB, 256, 0, stream>>>(feat, fb);
    dim3 grid(NB / 128, NB / 128);
    sim_kernel<<<grid, 256, 0, stream>>>(fb, labels, denom, possum, hsum, nposf, nhighf);
    finalize_kernel<<<1, 256, 0, stream>>>(denom, possum, hsum, nposf, nhighf, out);
}

// Round 2
// 288.488 us; speedup vs baseline: 1.2677x; 1.2677x over previous
//
#include <hip/hip_runtime.h>
#include <hip/hip_bf16.h>
#include <math.h>

typedef short bf16x8 __attribute__((ext_vector_type(8)));   // 8 bf16 in 4 VGPRs
typedef float f32x4 __attribute__((ext_vector_type(4)));

#define NB 8192
#define ND 256
#define NCLS 128          // label values are 0..99; pad to 128
#define INV_T 20.0f       // 1/TEMPERATURE
#define LOG2E_T 28.853900817779268f   // 20 * log2(e)  (exp(20x) = 2^(x*this))
#define HI_THR 1.2026042e6f           // exp(14): any sim>14 element exceeds this
#define SELF_TERM 4.85165195e8f       // exp(20)

// ---------------- Kernel 1: row L2-normalize, bf16 copy, class sums, histogram ---------
__global__ __launch_bounds__(256) void normalize_kernel(
    const float* __restrict__ feat, const int* __restrict__ labels,
    unsigned short* __restrict__ fb, float* __restrict__ classsum,
    int* __restrict__ count) {
    const int row = blockIdx.x;
    const int tid = threadIdx.x;           // 256 threads = 1 per column
    float v = feat[row * ND + tid];
    float ss = v * v;
    #pragma unroll
    for (int off = 32; off > 0; off >>= 1) ss += __shfl_xor(ss, off);
    __shared__ float part[4];
    if ((tid & 63) == 0) part[tid >> 6] = ss;
    __syncthreads();
    float tot = part[0] + part[1] + part[2] + part[3];
    float inv = rsqrtf(tot);
    float nv = v * inv;
    __hip_bfloat16 h = __float2bfloat16(nv);
    fb[row * ND + tid] = *reinterpret_cast<unsigned short*>(&h);
    const int lab = labels[row];
    atomicAdd(&classsum[lab * ND + tid], nv);
    if (tid == 0) atomicAdd(&count[lab], 1);
}

// ---------------- Kernel 2: sim tile + minimal fused epilogue ----------------
// grid (64,64); block 256 = 4 waves; block tile 128x128, wave tile 64x64 as
// 4x4 fragments of v_mfma_f32_16x16x32_bf16. Fast path computes only the
// per-row denominator; relax term goes through a ballot-guarded cold path.
__global__ __launch_bounds__(256, 4) void sim_kernel(
    const unsigned short* __restrict__ fb, const int* __restrict__ labels,
    float* __restrict__ denom, float* __restrict__ hsum,
    float* __restrict__ nhighf) {
    const int I0 = blockIdx.y * 128;
    const int J0 = blockIdx.x * 128;
    const int tid  = threadIdx.x;
    const int wave = tid >> 6;
    const int lane = tid & 63;
    const int wy = wave >> 1, wx = wave & 1;
    const int rbase = I0 + 64 * wy;        // this wave's A-row base
    const int cbase = J0 + 64 * wx;        // this wave's B-row (col) base
    const int l15  = lane & 15;
    const int quad = lane >> 4;

    f32x4 zero4 = {0.f, 0.f, 0.f, 0.f};
    f32x4 acc[4][4];
    #pragma unroll
    for (int fy = 0; fy < 4; ++fy)
        #pragma unroll
        for (int fx = 0; fx < 4; ++fx) acc[fy][fx] = zero4;

    // A-frag = f[rbase+l15][quad*8 + k0 + j]; B identical gather (B = f^T)
    const unsigned short* arow = fb + (size_t)(rbase + l15) * ND + quad * 8;
    const unsigned short* brow = fb + (size_t)(cbase + l15) * ND + quad * 8;

    #pragma unroll
    for (int k0 = 0; k0 < ND; k0 += 32) {
        bf16x8 a[4], b[4];
        #pragma unroll
        for (int f = 0; f < 4; ++f) {
            a[f] = *reinterpret_cast<const bf16x8*>(arow + (size_t)(16 * f) * ND + k0);
            b[f] = *reinterpret_cast<const bf16x8*>(brow + (size_t)(16 * f) * ND + k0);
        }
        #pragma unroll
        for (int fy = 0; fy < 4; ++fy)
            #pragma unroll
            for (int fx = 0; fx < 4; ++fx)
                acc[fy][fx] = __builtin_amdgcn_mfma_f32_16x16x32_bf16(
                    a[fy], b[fx], acc[fy][fx], 0, 0, 0);
    }

    // Epilogue. C/D layout: col = l15, row = quad*4 + r (m89/m91-verified).
    int anyhigh = 0;
    if (rbase != cbase) {
        // no diagonal elements possible in this wave's 64x64 tile
        #pragma unroll
        for (int fy = 0; fy < 4; ++fy) {
            #pragma unroll
            for (int r = 0; r < 4; ++r) {
                float d = 0.f;
                #pragma unroll
                for (int fx = 0; fx < 4; ++fx)
                    d += exp2f(acc[fy][fx][r] * LOG2E_T);
                anyhigh |= (d > HI_THR);
                #pragma unroll
                for (int off = 8; off > 0; off >>= 1) d += __shfl_xor(d, off);
                if (l15 == 0)
                    atomicAdd(&denom[rbase + 16 * fy + quad * 4 + r], d);
            }
        }
    } else {
        // diagonal tile: zero the col==row element before summing
        #pragma unroll
        for (int fy = 0; fy < 4; ++fy) {
            #pragma unroll
            for (int r = 0; r < 4; ++r) {
                const bool isdiag_lane = (l15 == quad * 4 + r);
                float d = 0.f;
                #pragma unroll
                for (int fx = 0; fx < 4; ++fx) {
                    float e = exp2f(acc[fy][fx][r] * LOG2E_T);
                    if (fx == fy && isdiag_lane) e = 0.f;
                    d += e;
                }
                anyhigh |= (d > HI_THR);
                #pragma unroll
                for (int off = 8; off > 0; off >>= 1) d += __shfl_xor(d, off);
                if (l15 == 0)
                    atomicAdd(&denom[rbase + 16 * fy + quad * 4 + r], d);
            }
        }
    }

    // Cold path: some element had sim > 14 (cos > 0.7) -> relax-term bookkeeping
    if (__any(anyhigh)) {
        int lcol[4];
        #pragma unroll
        for (int fx = 0; fx < 4; ++fx) lcol[fx] = labels[cbase + 16 * fx + l15];
        #pragma unroll
        for (int fy = 0; fy < 4; ++fy) {
            #pragma unroll
            for (int r = 0; r < 4; ++r) {
                const int row  = rbase + 16 * fy + quad * 4 + r;
                const int lrow = labels[row];
                float hs = 0.f, nh = 0.f;
                #pragma unroll
                for (int fx = 0; fx < 4; ++fx) {
                    const int col = cbase + 16 * fx + l15;
                    const float a = acc[fy][fx][r];
                    if (a > 0.7f && lcol[fx] == lrow && col != row) {
                        hs += exp2f(a * LOG2E_T);
                        nh += 1.f;
                    }
                }
                #pragma unroll
                for (int off = 8; off > 0; off >>= 1) {
                    hs += __shfl_xor(hs, off);
                    nh += __shfl_xor(nh, off);
                }
                if (l15 == 0 && nh > 0.f) {
                    atomicAdd(&hsum[row], hs);
                    atomicAdd(&nhighf[row], nh);
                }
            }
        }
    }
}

// ---------------- Kernel 3: scalar finalize ----------------
__global__ __launch_bounds__(256) void finalize_kernel(
    const float* __restrict__ denom, const float* __restrict__ hsum,
    const float* __restrict__ nhighf, const float* __restrict__ classsum,
    const int* __restrict__ count, const int* __restrict__ labels,
    float* __restrict__ out) {
    const int tid = threadIdx.x;
    // S = sum_c ||s_c||^2
    float S = 0.f;
    for (int i = tid; i < NCLS * ND; i += 256) {
        float x = classsum[i];
        S += x * x;
    }
    // npos_tot = sum_c n_c (n_c - 1)
    float NT = 0.f;
    if (tid < NCLS) {
        float nc = (float)count[tid];
        NT = nc * (nc - 1.f);
    }
    // per-row terms
    float SL = 0.f, RL = 0.f, NH = 0.f;
    for (int i = tid; i < NB; i += 256) {
        float np = (float)(count[labels[i]] - 1);
        SL += np * logf(denom[i] + 1e-8f);
        float h = hsum[i];
        if (h > 0.f) RL += logf(h + SELF_TERM);
        NH += nhighf[i];
    }
    #pragma unroll
    for (int off = 32; off > 0; off >>= 1) {
        S  += __shfl_xor(S, off);
        NT += __shfl_xor(NT, off);
        SL += __shfl_xor(SL, off);
        RL += __shfl_xor(RL, off);
        NH += __shfl_xor(NH, off);
    }
    __shared__ float part[4][5];
    if ((tid & 63) == 0) {
        int w = tid >> 6;
        part[w][0] = S; part[w][1] = NT; part[w][2] = SL;
        part[w][3] = RL; part[w][4] = NH;
    }
    __syncthreads();
    if (tid == 0) {
        float s  = part[0][0] + part[1][0] + part[2][0] + part[3][0];
        float nt = part[0][1] + part[1][1] + part[2][1] + part[3][1];
        float sl = part[0][2] + part[1][2] + part[2][2] + part[3][2];
        float rl = part[0][3] + part[1][3] + part[2][3] + part[3][3];
        float nh = part[0][4] + part[1][4] + part[2][4] + part[3][4];
        float pos_sim = (s - (float)NB) * INV_T;   // sum over positive pairs of sim
        float scl   = (nt > 0.f) ? (sl - pos_sim) / nt : 0.f;
        float relax = (nh > 0.f) ? rl / nh : 0.f;
        out[0] = scl + relax;
    }
}

extern "C" void kernel_launch(void* const* d_in, const int* in_sizes, int n_in,
                              void* d_out, int out_size, void* d_ws, size_t ws_size,
                              hipStream_t stream) {
    const float* feat  = (const float*)d_in[0];
    const int* labels  = (const int*)d_in[1];
    float* out = (float*)d_out;

    char* ws = (char*)d_ws;
    unsigned short* fb = (unsigned short*)ws;                 // 8192*256*2 = 4 MB
    float* denom    = (float*)(ws + (size_t)NB * ND * sizeof(unsigned short));
    float* hsum     = denom  + NB;
    float* nhighf   = hsum   + NB;
    float* classsum = nhighf + NB;          // NCLS * ND floats
    int*   count    = (int*)(classsum + NCLS * ND);

    // zero denom/hsum/nhighf/classsum/count in one contiguous memset
    size_t zero_bytes = (size_t)(3 * NB + NCLS * ND + NCLS) * sizeof(float);
    hipMemsetAsync(denom, 0, zero_bytes, stream);
    normalize_kernel<<<NB, 256, 0, stream>>>(feat, labels, fb, classsum, count);
    dim3 grid(NB / 128, NB / 128);
    sim_kernel<<<grid, 256, 0, stream>>>(fb, labels, denom, hsum, nhighf);
    finalize_kernel<<<1, 256, 0, stream>>>(denom, hsum, nhighf, classsum, count, labels, out);
}

// Round 3
// 268.586 us; speedup vs baseline: 1.3616x; 1.0741x over previous
//
#include <hip/hip_runtime.h>
#include <hip/hip_bf16.h>
#include <math.h>

typedef short bf16x8 __attribute__((ext_vector_type(8)));   // 8 bf16 in 4 VGPRs
typedef float f32x4 __attribute__((ext_vector_type(4)));

#define NB 8192
#define ND 256
#define NCLSR 100         // label values 0..99
#define NCLS 128          // padded sizing
#define BK 64             // K-chunk staged in LDS per iteration
#define INV_T 20.0f       // 1/TEMPERATURE
#define HI_THR 1.2026042e6f           // exp(14): any cos>0.7 element exceeds this
#define SELF_TERM 4.85165195e8f       // exp(20)

// ---------------- Kernel 1: row L2-normalize -> bf16 copy + inv-norm ----------------
// grid 2048 x 256; one wave per row; float4 loads, in-wave shuffle reduce.
__global__ __launch_bounds__(256) void normalize_kernel(
    const float* __restrict__ feat, const int* __restrict__ labels,
    unsigned short* __restrict__ fb, float* __restrict__ invn,
    int* __restrict__ count) {
    const int wave = threadIdx.x >> 6;
    const int lane = threadIdx.x & 63;
    const int row  = blockIdx.x * 4 + wave;
    float4 v = reinterpret_cast<const float4*>(feat + (size_t)row * ND)[lane];
    float ss = v.x * v.x + v.y * v.y + v.z * v.z + v.w * v.w;
    #pragma unroll
    for (int off = 32; off > 0; off >>= 1) ss += __shfl_xor(ss, off);
    const float inv = rsqrtf(ss);
    ushort4 o;
    __hip_bfloat16 h0 = __float2bfloat16(v.x * inv); o.x = *reinterpret_cast<unsigned short*>(&h0);
    __hip_bfloat16 h1 = __float2bfloat16(v.y * inv); o.y = *reinterpret_cast<unsigned short*>(&h1);
    __hip_bfloat16 h2 = __float2bfloat16(v.z * inv); o.z = *reinterpret_cast<unsigned short*>(&h2);
    __hip_bfloat16 h3 = __float2bfloat16(v.w * inv); o.w = *reinterpret_cast<unsigned short*>(&h3);
    reinterpret_cast<ushort4*>(fb + (size_t)row * ND)[lane] = o;
    if (lane == 0) {
        invn[row] = inv;
        atomicAdd(&count[labels[row]], 1);
    }
}

// ---------------- Kernel 1b: per-class sum vectors (for pos_sim identity) ----------------
// pos_sim = (sum_c ||s_c||^2 - B) / T  where s_c = sum of normalized rows of class c.
// grid (100, 8): block (c, s) scans rows [1024s, 1024s+1024), scalar label loads,
// accumulates matching rows in registers -> 256 atomics per block (205K total).
__global__ __launch_bounds__(256) void classsum_kernel(
    const float* __restrict__ feat, const float* __restrict__ invn,
    const int* __restrict__ labels, float* __restrict__ classsum) {
    const int c = blockIdx.x;
    const int r0 = blockIdx.y << 10;
    const int tid = threadIdx.x;
    float acc = 0.f;
    for (int r = r0; r < r0 + 1024; ++r) {
        if (labels[r] == c)                       // block-uniform scalar branch
            acc += feat[(size_t)r * ND + tid] * invn[r];
    }
    atomicAdd(&classsum[c * ND + tid], acc);
}

// ---------------- Kernel 2: triangular sim tiles, LDS-staged, fused epilogue ----------
// 2080 blocks = lower triangle (bi >= bj) of a 64x64 grid of 128x128 tiles.
// Block: 4 waves, wave tile 64x64 = 4x4 frags of v_mfma_f32_16x16x32_bf16.
// K-loop: BK=64 chunks staged via global_load_lds width-16 with XOR-granule
// swizzle (g' = g ^ (row&7)) so ds_read_b128 spreads 8 lanes/bank-group.
// Off-diagonal tiles feed denom twice: row-sums (rows I) + col-sums (rows J).
__global__ __launch_bounds__(256, 4) void sim_kernel(
    const unsigned short* __restrict__ fb, const int* __restrict__ labels,
    float* __restrict__ denom, float* __restrict__ hsum,
    float* __restrict__ nhighf) {
    __shared__ __align__(16) unsigned short ldsA[128 * BK];   // 16 KB
    __shared__ __align__(16) unsigned short ldsB[128 * BK];   // 16 KB

    // triangular decode: t -> (bi, bj), bi >= bj
    const int t = blockIdx.x;
    int bi = (int)((sqrtf((float)(8 * t + 1)) - 1.0f) * 0.5f);
    while ((bi + 1) * (bi + 2) / 2 <= t) ++bi;
    while (bi * (bi + 1) / 2 > t) --bi;
    const int bj = t - bi * (bi + 1) / 2;
    const int I0 = bi << 7;                 // tile rows
    const int J0 = bj << 7;                 // tile cols
    const bool isdiag = (bi == bj);

    const int tid  = threadIdx.x;
    const int wave = tid >> 6;
    const int lane = tid & 63;
    const int wy = wave >> 1, wx = wave & 1;
    const int l15  = lane & 15;
    const int quad = lane >> 4;
    const bool dw = isdiag && (wy == wx);   // wave tile contains diagonal elements

    f32x4 zero4 = {0.f, 0.f, 0.f, 0.f};
    f32x4 acc[4][4];
    #pragma unroll
    for (int fy = 0; fy < 4; ++fy)
        #pragma unroll
        for (int fx = 0; fx < 4; ++fx) acc[fy][fx] = zero4;

    for (int kk = 0; kk < ND; kk += BK) {
        __syncthreads();                    // protect LDS from prior-iter readers
        // stage A/B chunks: wave w covers block-local rows [32w, 32w+32)
        #pragma unroll
        for (int c = 0; c < 4; ++c) {
            const int Lg = (c << 6) + lane;               // granule index within wave's share
            const int row_loc = (wave << 5) + (Lg >> 3);  // 0..127
            const int g = (Lg & 7) ^ ((Lg >> 3) & 7);     // unswizzled k-granule
            const unsigned short* ga = fb + (size_t)(I0 + row_loc) * ND + kk + (g << 3);
            const unsigned short* gb = fb + (size_t)(J0 + row_loc) * ND + kk + (g << 3);
            __builtin_amdgcn_global_load_lds(
                (const __attribute__((address_space(1))) void*)ga,
                (__attribute__((address_space(3))) void*)(ldsA + (wave << 11) + (c << 9)),
                16, 0, 0);
            __builtin_amdgcn_global_load_lds(
                (const __attribute__((address_space(1))) void*)gb,
                (__attribute__((address_space(3))) void*)(ldsB + (wave << 11) + (c << 9)),
                16, 0, 0);
        }
        __syncthreads();                    // staging visible (compiler drains vmcnt)

        #pragma unroll
        for (int s = 0; s < 2; ++s) {       // two k0-steps of 32 within BK=64
            bf16x8 a[4], b[4];
            const int gsw = quad + (s << 2);
            #pragma unroll
            for (int f = 0; f < 4; ++f) {
                const int rowA = (wy << 6) + (f << 4) + l15;
                const int rowB = (wx << 6) + (f << 4) + l15;
                const int gp = gsw ^ (l15 & 7);
                a[f] = *reinterpret_cast<const bf16x8*>(ldsA + rowA * BK + (gp << 3));
                b[f] = *reinterpret_cast<const bf16x8*>(ldsB + rowB * BK + (gp << 3));
            }
            #pragma unroll
            for (int fy = 0; fy < 4; ++fy)
                #pragma unroll
                for (int fx = 0; fx < 4; ++fx)
                    acc[fy][fx] = __builtin_amdgcn_mfma_f32_16x16x32_bf16(
                        a[fy], b[fx], acc[fy][fx], 0, 0, 0);
        }
    }

    // Epilogue. C/D layout: col = l15, row = quad*4 + r (m89/m91-verified).
    const int rb = I0 + (wy << 6);          // wave's global row base
    const int cb = J0 + (wx << 6);          // wave's global col base
    int anyhigh = 0;
    float cs[4] = {0.f, 0.f, 0.f, 0.f};     // per-lane col partials (col = cb+16fx+l15)
    #pragma unroll
    for (int fy = 0; fy < 4; ++fy) {
        #pragma unroll
        for (int r = 0; r < 4; ++r) {
            const bool isdiag_lane = dw && (l15 == quad * 4 + r);
            float d = 0.f;
            #pragma unroll
            for (int fx = 0; fx < 4; ++fx) {
                float e = __expf(acc[fy][fx][r] * INV_T);
                if (fx == fy && isdiag_lane) e = 0.f;
                d += e;
                cs[fx] += e;
            }
            anyhigh |= (d > HI_THR);
            #pragma unroll
            for (int off = 8; off > 0; off >>= 1) d += __shfl_xor(d, off);
            if (l15 == 0)
                atomicAdd(&denom[rb + (fy << 4) + quad * 4 + r], d);
        }
    }
    if (!isdiag) {                          // col-sums feed the transposed tile's rows
        #pragma unroll
        for (int fx = 0; fx < 4; ++fx) {
            cs[fx] += __shfl_xor(cs[fx], 16);
            cs[fx] += __shfl_xor(cs[fx], 32);
        }
        if (quad == 0) {
            #pragma unroll
            for (int fx = 0; fx < 4; ++fx)
                atomicAdd(&denom[cb + (fx << 4) + l15], cs[fx]);
        }
    }

    // Cold path: some element had sim > 14 (cos > 0.7) -> relax-term bookkeeping.
    if (__any(anyhigh)) {
        int lcol[4];
        #pragma unroll
        for (int fx = 0; fx < 4; ++fx) lcol[fx] = labels[cb + (fx << 4) + l15];
        float hc[4] = {0.f, 0.f, 0.f, 0.f}, nc[4] = {0.f, 0.f, 0.f, 0.f};
        #pragma unroll
        for (int fy = 0; fy < 4; ++fy) {
            #pragma unroll
            for (int r = 0; r < 4; ++r) {
                const int row  = rb + (fy << 4) + quad * 4 + r;
                const int lrow = labels[row];
                float hs = 0.f, nh = 0.f;
                #pragma unroll
                for (int fx = 0; fx < 4; ++fx) {
                    const int col = cb + (fx << 4) + l15;
                    const float a = acc[fy][fx][r];
                    if (a > 0.7f && lcol[fx] == lrow && col != row) {
                        const float e = __expf(a * INV_T);
                        hs += e; nh += 1.f;
                        hc[fx] += e; nc[fx] += 1.f;
                    }
                }
                #pragma unroll
                for (int off = 8; off > 0; off >>= 1) {
                    hs += __shfl_xor(hs, off);
                    nh += __shfl_xor(nh, off);
                }
                if (l15 == 0 && nh > 0.f) {
                    atomicAdd(&hsum[row], hs);
                    atomicAdd(&nhighf[row], nh);
                }
            }
        }
        if (!isdiag) {
            #pragma unroll
            for (int fx = 0; fx < 4; ++fx) {
                hc[fx] += __shfl_xor(hc[fx], 16);
                hc[fx] += __shfl_xor(hc[fx], 32);
                nc[fx] += __shfl_xor(nc[fx], 16);
                nc[fx] += __shfl_xor(nc[fx], 32);
            }
            if (quad == 0) {
                #pragma unroll
                for (int fx = 0; fx < 4; ++fx) {
                    if (nc[fx] > 0.f) {
                        atomicAdd(&hsum[cb + (fx << 4) + l15], hc[fx]);
                        atomicAdd(&nhighf[cb + (fx << 4) + l15], nc[fx]);
                    }
                }
            }
        }
    }
}

// ---------------- Kernel 3: scalar finalize ----------------
__global__ __launch_bounds__(256) void finalize_kernel(
    const float* __restrict__ denom, const float* __restrict__ hsum,
    const float* __restrict__ nhighf, const float* __restrict__ classsum,
    const int* __restrict__ count, const int* __restrict__ labels,
    float* __restrict__ out) {
    const int tid = threadIdx.x;
    float S = 0.f;
    for (int i = tid; i < NCLSR * ND; i += 256) {
        float x = classsum[i];
        S += x * x;
    }
    float NT = 0.f;
    if (tid < NCLS) {
        float nc = (float)count[tid];
        NT = nc * (nc - 1.f);
    }
    float SL = 0.f, RL = 0.f, NH = 0.f;
    for (int i = tid; i < NB; i += 256) {
        float np = (float)(count[labels[i]] - 1);
        SL += np * logf(denom[i] + 1e-8f);
        float h = hsum[i];
        if (h > 0.f) RL += logf(h + SELF_TERM);
        NH += nhighf[i];
    }
    #pragma unroll
    for (int off = 32; off > 0; off >>= 1) {
        S  += __shfl_xor(S, off);
        NT += __shfl_xor(NT, off);
        SL += __shfl_xor(SL, off);
        RL += __shfl_xor(RL, off);
        NH += __shfl_xor(NH, off);
    }
    __shared__ float part[4][5];
    if ((tid & 63) == 0) {
        int w = tid >> 6;
        part[w][0] = S; part[w][1] = NT; part[w][2] = SL;
        part[w][3] = RL; part[w][4] = NH;
    }
    __syncthreads();
    if (tid == 0) {
        float s  = part[0][0] + part[1][0] + part[2][0] + part[3][0];
        float nt = part[0][1] + part[1][1] + part[2][1] + part[3][1];
        float sl = part[0][2] + part[1][2] + part[2][2] + part[3][2];
        float rl = part[0][3] + part[1][3] + part[2][3] + part[3][3];
        float nh = part[0][4] + part[1][4] + part[2][4] + part[3][4];
        float pos_sim = (s - (float)NB) * INV_T;   // sum of sim over positive pairs
        float scl   = (nt > 0.f) ? (sl - pos_sim) / nt : 0.f;
        float relax = (nh > 0.f) ? rl / nh : 0.f;
        out[0] = scl + relax;
    }
}

extern "C" void kernel_launch(void* const* d_in, const int* in_sizes, int n_in,
                              void* d_out, int out_size, void* d_ws, size_t ws_size,
                              hipStream_t stream) {
    const float* feat  = (const float*)d_in[0];
    const int* labels  = (const int*)d_in[1];
    float* out = (float*)d_out;

    char* ws = (char*)d_ws;
    unsigned short* fb = (unsigned short*)ws;                 // 8192*256*2 = 4 MB
    float* denom    = (float*)(ws + (size_t)NB * ND * sizeof(unsigned short));
    float* hsum     = denom  + NB;
    float* nhighf   = hsum   + NB;
    float* classsum = nhighf + NB;          // NCLSR * ND floats
    int*   count    = (int*)(classsum + NCLSR * ND);   // NCLS ints
    float* invn     = (float*)(count + NCLS);          // NB floats

    // zero denom/hsum/nhighf/classsum/count in one contiguous memset
    size_t zero_bytes = (size_t)(3 * NB + NCLSR * ND + NCLS) * sizeof(float);
    hipMemsetAsync(denom, 0, zero_bytes, stream);
    normalize_kernel<<<NB / 4, 256, 0, stream>>>(feat, labels, fb, invn, count);
    classsum_kernel<<<dim3(NCLSR, 8), 256, 0, stream>>>(feat, invn, labels, classsum);
    sim_kernel<<<2080, 256, 0, stream>>>(fb, labels, denom, hsum, nhighf);
    finalize_kernel<<<1, 256, 0, stream>>>(denom, hsum, nhighf, classsum, count, labels, out);
}

// Round 4
// 246.298 us; speedup vs baseline: 1.4848x; 1.0905x over previous
//
#include <hip/hip_runtime.h>
#include <hip/hip_bf16.h>
#include <math.h>

typedef short bf16x8 __attribute__((ext_vector_type(8)));   // 8 bf16 in 4 VGPRs
typedef float f32x4 __attribute__((ext_vector_type(4)));

#define NB 8192
#define ND 256
#define NCLSR 100         // label values 0..99
#define NCLS 128          // padded sizing
#define BK 64             // K-chunk staged in LDS per iteration
#define INV_T 20.0f       // 1/TEMPERATURE
#define LOG2E_T 28.853900817779268f   // 20*log2(e): exp(20x) = 2^(x*this)
#define HI_THR 1.2026042e6f           // exp(14): any cos>0.7 element exceeds this
#define SELF_TERM 4.85165195e8f       // exp(20)

// ---------------- Kernel 1: row L2-normalize -> bf16 copy + inv-norm ----------------
__global__ __launch_bounds__(256) void normalize_kernel(
    const float* __restrict__ feat, const int* __restrict__ labels,
    unsigned short* __restrict__ fb, float* __restrict__ invn,
    int* __restrict__ count) {
    const int wave = threadIdx.x >> 6;
    const int lane = threadIdx.x & 63;
    const int row  = blockIdx.x * 4 + wave;
    float4 v = reinterpret_cast<const float4*>(feat + (size_t)row * ND)[lane];
    float ss = v.x * v.x + v.y * v.y + v.z * v.z + v.w * v.w;
    #pragma unroll
    for (int off = 32; off > 0; off >>= 1) ss += __shfl_xor(ss, off);
    const float inv = rsqrtf(ss);
    ushort4 o;
    __hip_bfloat16 h0 = __float2bfloat16(v.x * inv); o.x = *reinterpret_cast<unsigned short*>(&h0);
    __hip_bfloat16 h1 = __float2bfloat16(v.y * inv); o.y = *reinterpret_cast<unsigned short*>(&h1);
    __hip_bfloat16 h2 = __float2bfloat16(v.z * inv); o.z = *reinterpret_cast<unsigned short*>(&h2);
    __hip_bfloat16 h3 = __float2bfloat16(v.w * inv); o.w = *reinterpret_cast<unsigned short*>(&h3);
    reinterpret_cast<ushort4*>(fb + (size_t)row * ND)[lane] = o;
    if (lane == 0) {
        invn[row] = inv;
        atomicAdd(&count[labels[row]], 1);
    }
}

// ---------------- Kernel 1b: per-class sum vectors ----------------
// pos_sim = (sum_c ||s_c||^2 - B)/T with s_c = sum of normalized rows of class c.
// grid (100, 8). Labels+invn staged in LDS so the scan has no serial global-load
// chain; matching feat loads are independent and pipeline.
__global__ __launch_bounds__(256) void classsum_kernel(
    const float* __restrict__ feat, const float* __restrict__ invn,
    const int* __restrict__ labels, float* __restrict__ classsum) {
    __shared__ int   slab[1024];
    __shared__ float sinv[1024];
    const int c   = blockIdx.x;
    const int r0  = blockIdx.y << 10;
    const int tid = threadIdx.x;
    #pragma unroll
    for (int i = 0; i < 4; ++i) {
        slab[tid + 256 * i] = labels[r0 + tid + 256 * i];
        sinv[tid + 256 * i] = invn[r0 + tid + 256 * i];
    }
    __syncthreads();
    float acc = 0.f;
    #pragma unroll 8
    for (int r = 0; r < 1024; ++r) {
        if (slab[r] == c)
            acc += feat[(size_t)(r0 + r) * ND + tid] * sinv[r];
    }
    atomicAdd(&classsum[c * ND + tid], acc);
}

// ---------------- Kernel 2: triangular sim tiles, LDS-staged, fused epilogue ----------
// 2080 blocks = lower triangle (bi >= bj). Block: 4 waves, 128x128 tile; wave 64x64
// as 4x4 frags of v_mfma_f32_16x16x32_bf16. BK=64 LDS staging via global_load_lds
// width-16, XOR-granule swizzle baked into the GLOBAL address (LDS side stays
// lane-contiguous as the instruction requires). launch_bounds (256,3): 170-reg
// budget so the 64-AGPR accumulator + staging regs do NOT spill (R3's 228 MB
// scratch traffic came from the 128-reg cap at min-waves=4).
__global__ __launch_bounds__(256, 3) void sim_kernel(
    const unsigned short* __restrict__ fb, const int* __restrict__ labels,
    float* __restrict__ denom, float* __restrict__ hsum,
    float* __restrict__ nhighf) {
    __shared__ __align__(16) unsigned short ldsA[128 * BK];   // 16 KB
    __shared__ __align__(16) unsigned short ldsB[128 * BK];   // 16 KB

    // triangular decode: t -> (bi, bj), bi >= bj
    const int t = blockIdx.x;
    int bi = (int)((sqrtf((float)(8 * t + 1)) - 1.0f) * 0.5f);
    while ((bi + 1) * (bi + 2) / 2 <= t) ++bi;
    while (bi * (bi + 1) / 2 > t) --bi;
    const int bj = t - bi * (bi + 1) / 2;
    const int I0 = bi << 7;
    const int J0 = bj << 7;
    const bool isdiag = (bi == bj);

    const int tid  = threadIdx.x;
    const int wave = tid >> 6;
    const int lane = tid & 63;
    const int wy = wave >> 1, wx = wave & 1;
    const int l15  = lane & 15;
    const int quad = lane >> 4;
    const bool dw = isdiag && (wy == wx);

    // staging offsets, computed once: chunk c covers block-local row
    // row_loc = 32*wave + (Lg>>3), swizzled granule g = (Lg&7)^((Lg>>3)&7)
    int offRC[4];
    #pragma unroll
    for (int c = 0; c < 4; ++c) {
        const int Lg = (c << 6) + lane;
        const int row_loc = (wave << 5) + (Lg >> 3);
        const int g = (Lg & 7) ^ ((Lg >> 3) & 7);
        offRC[c] = row_loc * ND + (g << 3);
    }
    const unsigned short* baseA = fb + (size_t)I0 * ND;
    const unsigned short* baseB = fb + (size_t)J0 * ND;

    f32x4 zero4 = {0.f, 0.f, 0.f, 0.f};
    f32x4 acc[4][4];
    #pragma unroll
    for (int fy = 0; fy < 4; ++fy)
        #pragma unroll
        for (int fx = 0; fx < 4; ++fx) acc[fy][fx] = zero4;

    for (int kk = 0; kk < ND; kk += BK) {
        __syncthreads();                    // protect LDS from prior-iter readers
        #pragma unroll
        for (int c = 0; c < 4; ++c) {
            __builtin_amdgcn_global_load_lds(
                (const __attribute__((address_space(1))) void*)(baseA + offRC[c] + kk),
                (__attribute__((address_space(3))) void*)(ldsA + (wave << 11) + (c << 9)),
                16, 0, 0);
            __builtin_amdgcn_global_load_lds(
                (const __attribute__((address_space(1))) void*)(baseB + offRC[c] + kk),
                (__attribute__((address_space(3))) void*)(ldsB + (wave << 11) + (c << 9)),
                16, 0, 0);
        }
        __syncthreads();                    // staging visible

        #pragma unroll
        for (int s = 0; s < 2; ++s) {
            bf16x8 a[4], b[4];
            const int gsw = quad + (s << 2);
            #pragma unroll
            for (int f = 0; f < 4; ++f) {
                const int rowA = (wy << 6) + (f << 4) + l15;
                const int rowB = (wx << 6) + (f << 4) + l15;
                const int gp = gsw ^ (l15 & 7);
                a[f] = *reinterpret_cast<const bf16x8*>(ldsA + rowA * BK + (gp << 3));
                b[f] = *reinterpret_cast<const bf16x8*>(ldsB + rowB * BK + (gp << 3));
            }
            #pragma unroll
            for (int fy = 0; fy < 4; ++fy)
                #pragma unroll
                for (int fx = 0; fx < 4; ++fx)
                    acc[fy][fx] = __builtin_amdgcn_mfma_f32_16x16x32_bf16(
                        a[fy], b[fx], acc[fy][fx], 0, 0, 0);
        }
    }

    // Epilogue. C/D layout: col = l15, row = quad*4 + r (m89/m91-verified).
    const int rb = I0 + (wy << 6);
    const int cb = J0 + (wx << 6);
    int anyhigh = 0;
    float cs[4] = {0.f, 0.f, 0.f, 0.f};
    #pragma unroll
    for (int fy = 0; fy < 4; ++fy) {
        #pragma unroll
        for (int r = 0; r < 4; ++r) {
            const bool isdiag_lane = dw && (l15 == quad * 4 + r);
            float d = 0.f;
            #pragma unroll
            for (int fx = 0; fx < 4; ++fx) {
                float e = exp2f(acc[fy][fx][r] * LOG2E_T);
                if (fx == fy && isdiag_lane) e = 0.f;
                d += e;
                cs[fx] += e;
            }
            anyhigh |= (d > HI_THR);
            #pragma unroll
            for (int off = 8; off > 0; off >>= 1) d += __shfl_xor(d, off);
            if (l15 == 0)
                atomicAdd(&denom[rb + (fy << 4) + quad * 4 + r], d);
        }
    }
    if (!isdiag) {                          // col-sums feed the mirror tile's rows
        #pragma unroll
        for (int fx = 0; fx < 4; ++fx) {
            cs[fx] += __shfl_xor(cs[fx], 16);
            cs[fx] += __shfl_xor(cs[fx], 32);
        }
        if (quad == 0) {
            #pragma unroll
            for (int fx = 0; fx < 4; ++fx)
                atomicAdd(&denom[cb + (fx << 4) + l15], cs[fx]);
        }
    }

    // Cold path: some element had sim > 14 (cos > 0.7) -> relax-term bookkeeping.
    if (__any(anyhigh)) {
        int lcol[4];
        #pragma unroll
        for (int fx = 0; fx < 4; ++fx) lcol[fx] = labels[cb + (fx << 4) + l15];
        float hc[4] = {0.f, 0.f, 0.f, 0.f}, nc[4] = {0.f, 0.f, 0.f, 0.f};
        #pragma unroll
        for (int fy = 0; fy < 4; ++fy) {
            #pragma unroll
            for (int r = 0; r < 4; ++r) {
                const int row  = rb + (fy << 4) + quad * 4 + r;
                const int lrow = labels[row];
                float hs = 0.f, nh = 0.f;
                #pragma unroll
                for (int fx = 0; fx < 4; ++fx) {
                    const int col = cb + (fx << 4) + l15;
                    const float a = acc[fy][fx][r];
                    if (a > 0.7f && lcol[fx] == lrow && col != row) {
                        const float e = exp2f(a * LOG2E_T);
                        hs += e; nh += 1.f;
                        hc[fx] += e; nc[fx] += 1.f;
                    }
                }
                #pragma unroll
                for (int off = 8; off > 0; off >>= 1) {
                    hs += __shfl_xor(hs, off);
                    nh += __shfl_xor(nh, off);
                }
                if (l15 == 0 && nh > 0.f) {
                    atomicAdd(&hsum[row], hs);
                    atomicAdd(&nhighf[row], nh);
                }
            }
        }
        if (!isdiag) {
            #pragma unroll
            for (int fx = 0; fx < 4; ++fx) {
                hc[fx] += __shfl_xor(hc[fx], 16);
                hc[fx] += __shfl_xor(hc[fx], 32);
                nc[fx] += __shfl_xor(nc[fx], 16);
                nc[fx] += __shfl_xor(nc[fx], 32);
            }
            if (quad == 0) {
                #pragma unroll
                for (int fx = 0; fx < 4; ++fx) {
                    if (nc[fx] > 0.f) {
                        atomicAdd(&hsum[cb + (fx << 4) + l15], hc[fx]);
                        atomicAdd(&nhighf[cb + (fx << 4) + l15], nc[fx]);
                    }
                }
            }
        }
    }
}

// ---------------- Kernel 3: scalar finalize ----------------
__global__ __launch_bounds__(256) void finalize_kernel(
    const float* __restrict__ denom, const float* __restrict__ hsum,
    const float* __restrict__ nhighf, const float* __restrict__ classsum,
    const int* __restrict__ count, const int* __restrict__ labels,
    float* __restrict__ out) {
    const int tid = threadIdx.x;
    float S = 0.f;
    for (int i = tid; i < NCLSR * ND; i += 256) {
        float x = classsum[i];
        S += x * x;
    }
    float NT = 0.f;
    if (tid < NCLS) {
        float nc = (float)count[tid];
        NT = nc * (nc - 1.f);
    }
    float SL = 0.f, RL = 0.f, NH = 0.f;
    for (int i = tid; i < NB; i += 256) {
        float np = (float)(count[labels[i]] - 1);
        SL += np * logf(denom[i] + 1e-8f);
        float h = hsum[i];
        if (h > 0.f) RL += logf(h + SELF_TERM);
        NH += nhighf[i];
    }
    #pragma unroll
    for (int off = 32; off > 0; off >>= 1) {
        S  += __shfl_xor(S, off);
        NT += __shfl_xor(NT, off);
        SL += __shfl_xor(SL, off);
        RL += __shfl_xor(RL, off);
        NH += __shfl_xor(NH, off);
    }
    __shared__ float part[4][5];
    if ((tid & 63) == 0) {
        int w = tid >> 6;
        part[w][0] = S; part[w][1] = NT; part[w][2] = SL;
        part[w][3] = RL; part[w][4] = NH;
    }
    __syncthreads();
    if (tid == 0) {
        float s  = part[0][0] + part[1][0] + part[2][0] + part[3][0];
        float nt = part[0][1] + part[1][1] + part[2][1] + part[3][1];
        float sl = part[0][2] + part[1][2] + part[2][2] + part[3][2];
        float rl = part[0][3] + part[1][3] + part[2][3] + part[3][3];
        float nh = part[0][4] + part[1][4] + part[2][4] + part[3][4];
        float pos_sim = (s - (float)NB) * INV_T;
        float scl   = (nt > 0.f) ? (sl - pos_sim) / nt : 0.f;
        float relax = (nh > 0.f) ? rl / nh : 0.f;
        out[0] = scl + relax;
    }
}

extern "C" void kernel_launch(void* const* d_in, const int* in_sizes, int n_in,
                              void* d_out, int out_size, void* d_ws, size_t ws_size,
                              hipStream_t stream) {
    const float* feat  = (const float*)d_in[0];
    const int* labels  = (const int*)d_in[1];
    float* out = (float*)d_out;

    char* ws = (char*)d_ws;
    unsigned short* fb = (unsigned short*)ws;                 // 4 MB
    float* denom    = (float*)(ws + (size_t)NB * ND * sizeof(unsigned short));
    float* hsum     = denom  + NB;
    float* nhighf   = hsum   + NB;
    float* classsum = nhighf + NB;                     // NCLSR * ND floats
    int*   count    = (int*)(classsum + NCLSR * ND);   // NCLS ints
    float* invn     = (float*)(count + NCLS);          // NB floats

    size_t zero_bytes = (size_t)(3 * NB + NCLSR * ND + NCLS) * sizeof(float);
    hipMemsetAsync(denom, 0, zero_bytes, stream);
    normalize_kernel<<<NB / 4, 256, 0, stream>>>(feat, labels, fb, invn, count);
    classsum_kernel<<<dim3(NCLSR, 8), 256, 0, stream>>>(feat, invn, labels, classsum);
    sim_kernel<<<2080, 256, 0, stream>>>(fb, labels, denom, hsum, nhighf);
    finalize_kernel<<<1, 256, 0, stream>>>(denom, hsum, nhighf, classsum, count, labels, out);
}

// Round 5
// 190.850 us; speedup vs baseline: 1.9162x; 1.2905x over previous
//
#include <hip/hip_runtime.h>
#include <hip/hip_bf16.h>
#include <math.h>

typedef short bf16x8 __attribute__((ext_vector_type(8)));   // 8 bf16 in 4 VGPRs
typedef float f32x4 __attribute__((ext_vector_type(4)));

#define NB 8192
#define ND 256
#define NCLSR 100         // label values 0..99
#define NSTRIP 8          // classsum strips
#define BK 64             // K-chunk staged in LDS per iteration
#define INV_T 20.0f       // 1/TEMPERATURE
#define LOG2E_T 28.853900817779268f   // 20*log2(e): exp(20x) = 2^(x*this)
#define HI_THR 1.2026042e6f           // exp(14): any cos>0.7 element exceeds this
#define SELF_TERM 4.85165195e8f       // exp(20)

// ---------------- Kernel 1: row L2-normalize -> bf16 copy; zero hsum/nhighf ----------
__global__ __launch_bounds__(256) void normalize_kernel(
    const float* __restrict__ feat, unsigned short* __restrict__ fb,
    float* __restrict__ hsum, float* __restrict__ nhighf) {
    const int wave = threadIdx.x >> 6;
    const int lane = threadIdx.x & 63;
    const int row  = blockIdx.x * 4 + wave;
    float4 v = reinterpret_cast<const float4*>(feat + (size_t)row * ND)[lane];
    float ss = v.x * v.x + v.y * v.y + v.z * v.z + v.w * v.w;
    #pragma unroll
    for (int off = 32; off > 0; off >>= 1) ss += __shfl_xor(ss, off);
    const float inv = rsqrtf(ss);
    ushort4 o;
    __hip_bfloat16 h0 = __float2bfloat16(v.x * inv); o.x = *reinterpret_cast<unsigned short*>(&h0);
    __hip_bfloat16 h1 = __float2bfloat16(v.y * inv); o.y = *reinterpret_cast<unsigned short*>(&h1);
    __hip_bfloat16 h2 = __float2bfloat16(v.z * inv); o.z = *reinterpret_cast<unsigned short*>(&h2);
    __hip_bfloat16 h3 = __float2bfloat16(v.w * inv); o.w = *reinterpret_cast<unsigned short*>(&h3);
    reinterpret_cast<ushort4*>(fb + (size_t)row * ND)[lane] = o;
    // spare work: zero the cold-path accumulators (sim runs after us)
    if (blockIdx.x < 32) {
        const int i = (blockIdx.x << 8) + threadIdx.x;
        hsum[i] = 0.f;
        nhighf[i] = 0.f;
    }
}

// ---------------- Kernel 1b: per-class partial sums (no atomics) ----------------
// pos_sim = (sum_c ||s_c||^2 - B)/T with s_c = sum of bf16-normalized rows of class c.
// grid (100, 8): block (c,s) scans rows [1024s, 1024s+1024) with labels in LDS,
// writes cpart[(c*8+s)*256 + tid] and pcnt[c*8+s]. Merged in finalize.
__global__ __launch_bounds__(256) void classsum_kernel(
    const unsigned short* __restrict__ fb, const int* __restrict__ labels,
    float* __restrict__ cpart, int* __restrict__ pcnt) {
    __shared__ int slab[1024];
    const int c   = blockIdx.x;
    const int s   = blockIdx.y;
    const int r0  = s << 10;
    const int tid = threadIdx.x;
    #pragma unroll
    for (int i = 0; i < 4; ++i)
        slab[tid + 256 * i] = labels[r0 + tid + 256 * i];
    __syncthreads();
    float acc = 0.f;
    int cnt = 0;
    #pragma unroll 8
    for (int r = 0; r < 1024; ++r) {
        if (slab[r] == c) {                    // block-uniform branch
            unsigned int u = fb[(size_t)(r0 + r) * ND + tid];
            u <<= 16;
            acc += *reinterpret_cast<float*>(&u);
            ++cnt;
        }
    }
    cpart[(size_t)(c * NSTRIP + s) * 256 + tid] = acc;
    if (tid == 0) pcnt[c * NSTRIP + s] = cnt;
}

// ---------------- Kernel 2: triangular sim tiles, LDS-staged, atomic-free ----------
// 2080 blocks = lower triangle (bi >= bj). Block: 4 waves, 128x128 tile; wave 64x64
// as 4x4 frags of v_mfma_f32_16x16x32_bf16. BK=64 LDS staging via global_load_lds
// width-16 with XOR-granule swizzle baked into the GLOBAL address.
// Row/col exp-sum partials go through 2 KB LDS and are stored (plain coalesced
// stores, no atomics) to Q: row partials at Q[bi][bj][r], col partials at the
// mirror slot Q[bj][bi][c]. Every slot of the 64x64 grid written exactly once.
__global__ __launch_bounds__(256, 3) void sim_kernel(
    const unsigned short* __restrict__ fb, const int* __restrict__ labels,
    float* __restrict__ Q, float* __restrict__ hsum,
    float* __restrict__ nhighf) {
    __shared__ __align__(16) unsigned short ldsA[128 * BK];   // 16 KB
    __shared__ __align__(16) unsigned short ldsB[128 * BK];   // 16 KB
    __shared__ float ldsRow[2][128];                          // [wx][local row]
    __shared__ float ldsCol[2][128];                          // [wy][local col]

    // triangular decode: t -> (bi, bj), bi >= bj
    const int t = blockIdx.x;
    int bi = (int)((sqrtf((float)(8 * t + 1)) - 1.0f) * 0.5f);
    while ((bi + 1) * (bi + 2) / 2 <= t) ++bi;
    while (bi * (bi + 1) / 2 > t) --bi;
    const int bj = t - bi * (bi + 1) / 2;
    const int I0 = bi << 7;
    const int J0 = bj << 7;
    const bool isdiag = (bi == bj);

    const int tid  = threadIdx.x;
    const int wave = tid >> 6;
    const int lane = tid & 63;
    const int wy = wave >> 1, wx = wave & 1;
    const int l15  = lane & 15;
    const int quad = lane >> 4;
    const bool dw = isdiag && (wy == wx);

    int offRC[4];
    #pragma unroll
    for (int c = 0; c < 4; ++c) {
        const int Lg = (c << 6) + lane;
        const int row_loc = (wave << 5) + (Lg >> 3);
        const int g = (Lg & 7) ^ ((Lg >> 3) & 7);
        offRC[c] = row_loc * ND + (g << 3);
    }
    const unsigned short* baseA = fb + (size_t)I0 * ND;
    const unsigned short* baseB = fb + (size_t)J0 * ND;

    f32x4 zero4 = {0.f, 0.f, 0.f, 0.f};
    f32x4 acc[4][4];
    #pragma unroll
    for (int fy = 0; fy < 4; ++fy)
        #pragma unroll
        for (int fx = 0; fx < 4; ++fx) acc[fy][fx] = zero4;

    for (int kk = 0; kk < ND; kk += BK) {
        __syncthreads();
        #pragma unroll
        for (int c = 0; c < 4; ++c) {
            __builtin_amdgcn_global_load_lds(
                (const __attribute__((address_space(1))) void*)(baseA + offRC[c] + kk),
                (__attribute__((address_space(3))) void*)(ldsA + (wave << 11) + (c << 9)),
                16, 0, 0);
            __builtin_amdgcn_global_load_lds(
                (const __attribute__((address_space(1))) void*)(baseB + offRC[c] + kk),
                (__attribute__((address_space(3))) void*)(ldsB + (wave << 11) + (c << 9)),
                16, 0, 0);
        }
        __syncthreads();

        #pragma unroll
        for (int s = 0; s < 2; ++s) {
            bf16x8 a[4], b[4];
            const int gsw = quad + (s << 2);
            #pragma unroll
            for (int f = 0; f < 4; ++f) {
                const int rowA = (wy << 6) + (f << 4) + l15;
                const int rowB = (wx << 6) + (f << 4) + l15;
                const int gp = gsw ^ (l15 & 7);
                a[f] = *reinterpret_cast<const bf16x8*>(ldsA + rowA * BK + (gp << 3));
                b[f] = *reinterpret_cast<const bf16x8*>(ldsB + rowB * BK + (gp << 3));
            }
            #pragma unroll
            for (int fy = 0; fy < 4; ++fy)
                #pragma unroll
                for (int fx = 0; fx < 4; ++fx)
                    acc[fy][fx] = __builtin_amdgcn_mfma_f32_16x16x32_bf16(
                        a[fy], b[fx], acc[fy][fx], 0, 0, 0);
        }
    }

    // Epilogue. C/D layout: col = l15, row = quad*4 + r (m89/m91-verified).
    const int rb = I0 + (wy << 6);
    const int cb = J0 + (wx << 6);
    int anyhigh = 0;
    float cs[4] = {0.f, 0.f, 0.f, 0.f};
    #pragma unroll
    for (int fy = 0; fy < 4; ++fy) {
        #pragma unroll
        for (int r = 0; r < 4; ++r) {
            const bool isdiag_lane = dw && (l15 == quad * 4 + r);
            float d = 0.f;
            #pragma unroll
            for (int fx = 0; fx < 4; ++fx) {
                float e = exp2f(acc[fy][fx][r] * LOG2E_T);
                if (fx == fy && isdiag_lane) e = 0.f;
                d += e;
                cs[fx] += e;
            }
            anyhigh |= (d > HI_THR);
            #pragma unroll
            for (int off = 8; off > 0; off >>= 1) d += __shfl_xor(d, off);
            if (l15 == 0)
                ldsRow[wx][(wy << 6) + (fy << 4) + (quad << 2) + r] = d;
        }
    }
    if (!isdiag) {
        #pragma unroll
        for (int fx = 0; fx < 4; ++fx) {
            cs[fx] += __shfl_xor(cs[fx], 16);
            cs[fx] += __shfl_xor(cs[fx], 32);
        }
        if (quad == 0) {
            #pragma unroll
            for (int fx = 0; fx < 4; ++fx)
                ldsCol[wy][(wx << 6) + (fx << 4) + l15] = cs[fx];
        }
    }
    __syncthreads();
    if (tid < 128) {
        Q[(size_t)(bi * 64 + bj) * 128 + tid] = ldsRow[0][tid] + ldsRow[1][tid];
    } else if (!isdiag) {
        const int c2 = tid - 128;
        Q[(size_t)(bj * 64 + bi) * 128 + c2] = ldsCol[0][c2] + ldsCol[1][c2];
    }

    // Cold path: some element had sim > 14 (cos > 0.7) -> relax-term bookkeeping.
    if (__any(anyhigh)) {
        int lcol[4];
        #pragma unroll
        for (int fx = 0; fx < 4; ++fx) lcol[fx] = labels[cb + (fx << 4) + l15];
        float hc[4] = {0.f, 0.f, 0.f, 0.f}, nc[4] = {0.f, 0.f, 0.f, 0.f};
        #pragma unroll
        for (int fy = 0; fy < 4; ++fy) {
            #pragma unroll
            for (int r = 0; r < 4; ++r) {
                const int row  = rb + (fy << 4) + quad * 4 + r;
                const int lrow = labels[row];
                float hs = 0.f, nh = 0.f;
                #pragma unroll
                for (int fx = 0; fx < 4; ++fx) {
                    const int col = cb + (fx << 4) + l15;
                    const float a = acc[fy][fx][r];
                    if (a > 0.7f && lcol[fx] == lrow && col != row) {
                        const float e = exp2f(a * LOG2E_T);
                        hs += e; nh += 1.f;
                        hc[fx] += e; nc[fx] += 1.f;
                    }
                }
                #pragma unroll
                for (int off = 8; off > 0; off >>= 1) {
                    hs += __shfl_xor(hs, off);
                    nh += __shfl_xor(nh, off);
                }
                if (l15 == 0 && nh > 0.f) {
                    atomicAdd(&hsum[row], hs);
                    atomicAdd(&nhighf[row], nh);
                }
            }
        }
        if (!isdiag) {
            #pragma unroll
            for (int fx = 0; fx < 4; ++fx) {
                hc[fx] += __shfl_xor(hc[fx], 16);
                hc[fx] += __shfl_xor(hc[fx], 32);
                nc[fx] += __shfl_xor(nc[fx], 16);
                nc[fx] += __shfl_xor(nc[fx], 32);
            }
            if (quad == 0) {
                #pragma unroll
                for (int fx = 0; fx < 4; ++fx) {
                    if (nc[fx] > 0.f) {
                        atomicAdd(&hsum[cb + (fx << 4) + l15], hc[fx]);
                        atomicAdd(&nhighf[cb + (fx << 4) + l15], nc[fx]);
                    }
                }
            }
        }
    }
}

// ---------------- Kernel 2b: fold Q partials into denom ----------------
// grid 64: block g computes denom[g*128 + r] = sum_s Q[g][s][r].
__global__ __launch_bounds__(256) void reduce_kernel(
    const float* __restrict__ Q, float* __restrict__ denom) {
    const int g = blockIdx.x;
    const int t = threadIdx.x;
    const int r = t & 127;
    const int sh = t >> 7;
    const float* base = Q + (size_t)g * 64 * 128;
    float s = 0.f;
    #pragma unroll 8
    for (int i = 0; i < 32; ++i)
        s += base[(size_t)(sh * 32 + i) * 128 + r];
    __shared__ float red[256];
    red[t] = s;
    __syncthreads();
    if (t < 128) denom[g * 128 + t] = red[t] + red[t + 128];
}

// ---------------- Kernel 3: scalar finalize ----------------
__global__ __launch_bounds__(256) void finalize_kernel(
    const float* __restrict__ denom, const float* __restrict__ hsum,
    const float* __restrict__ nhighf, const float* __restrict__ cpart,
    const int* __restrict__ pcnt, const int* __restrict__ labels,
    float* __restrict__ out) {
    const int tid = threadIdx.x;
    // class counts from strip partials
    __shared__ float cnt_lds[NCLSR];
    if (tid < NCLSR) {
        int c = 0;
        #pragma unroll
        for (int s = 0; s < NSTRIP; ++s) c += pcnt[tid * NSTRIP + s];
        cnt_lds[tid] = (float)c;
    }
    __syncthreads();
    // S = sum_c ||s_c||^2 (merge strip partials per component)
    float S = 0.f;
    for (int c = 0; c < NCLSR; ++c) {
        float x = 0.f;
        #pragma unroll
        for (int s = 0; s < NSTRIP; ++s)
            x += cpart[(size_t)(c * NSTRIP + s) * 256 + tid];
        S += x * x;
    }
    // NT = sum_c n_c (n_c - 1)
    float NT = 0.f;
    if (tid < NCLSR) {
        float nc = cnt_lds[tid];
        NT = nc * (nc - 1.f);
    }
    // per-row terms
    float SL = 0.f, RL = 0.f, NH = 0.f;
    for (int i = tid; i < NB; i += 256) {
        float np = cnt_lds[labels[i]] - 1.f;
        SL += np * logf(denom[i] + 1e-8f);
        float h = hsum[i];
        if (h > 0.f) RL += logf(h + SELF_TERM);
        NH += nhighf[i];
    }
    #pragma unroll
    for (int off = 32; off > 0; off >>= 1) {
        S  += __shfl_xor(S, off);
        NT += __shfl_xor(NT, off);
        SL += __shfl_xor(SL, off);
        RL += __shfl_xor(RL, off);
        NH += __shfl_xor(NH, off);
    }
    __shared__ float part[4][5];
    if ((tid & 63) == 0) {
        int w = tid >> 6;
        part[w][0] = S; part[w][1] = NT; part[w][2] = SL;
        part[w][3] = RL; part[w][4] = NH;
    }
    __syncthreads();
    if (tid == 0) {
        float s  = part[0][0] + part[1][0] + part[2][0] + part[3][0];
        float nt = part[0][1] + part[1][1] + part[2][1] + part[3][1];
        float sl = part[0][2] + part[1][2] + part[2][2] + part[3][2];
        float rl = part[0][3] + part[1][3] + part[2][3] + part[3][3];
        float nh = part[0][4] + part[1][4] + part[2][4] + part[3][4];
        float pos_sim = (s - (float)NB) * INV_T;
        float scl   = (nt > 0.f) ? (sl - pos_sim) / nt : 0.f;
        float relax = (nh > 0.f) ? rl / nh : 0.f;
        out[0] = scl + relax;
    }
}

extern "C" void kernel_launch(void* const* d_in, const int* in_sizes, int n_in,
                              void* d_out, int out_size, void* d_ws, size_t ws_size,
                              hipStream_t stream) {
    const float* feat  = (const float*)d_in[0];
    const int* labels  = (const int*)d_in[1];
    float* out = (float*)d_out;

    char* ws = (char*)d_ws;
    unsigned short* fb = (unsigned short*)ws;                 // 4 MB
    float* Q      = (float*)(ws + (size_t)NB * ND * sizeof(unsigned short)); // 2 MB
    float* denom  = Q + 64 * 64 * 128;
    float* hsum   = denom  + NB;
    float* nhighf = hsum   + NB;
    float* cpart  = nhighf + NB;                   // 100*8*256 floats
    int*   pcnt   = (int*)(cpart + NCLSR * NSTRIP * 256);

    normalize_kernel<<<NB / 4, 256, 0, stream>>>(feat, fb, hsum, nhighf);
    classsum_kernel<<<dim3(NCLSR, NSTRIP), 256, 0, stream>>>(fb, labels, cpart, pcnt);
    sim_kernel<<<2080, 256, 0, stream>>>(fb, labels, Q, hsum, nhighf);
    reduce_kernel<<<64, 256, 0, stream>>>(Q, denom);
    finalize_kernel<<<1, 256, 0, stream>>>(denom, hsum, nhighf, cpart, pcnt, labels, out);
}

// Round 6
// 153.758 us; speedup vs baseline: 2.3785x; 1.2412x over previous
//
#include <hip/hip_runtime.h>
#include <hip/hip_bf16.h>
#include <math.h>

typedef short bf16x8 __attribute__((ext_vector_type(8)));   // 8 bf16 in 4 VGPRs
typedef float f32x4 __attribute__((ext_vector_type(4)));

#define NB 8192
#define ND 256
#define NCLSR 100         // label values 0..99
#define BK 64             // K-chunk staged in LDS per iteration
#define INV_T 20.0f       // 1/TEMPERATURE
#define LOG2E_T 28.853900817779268f   // 20*log2(e): exp(20x) = 2^(x*this)
#define HI_THR 1.2026042e6f           // exp(14): any cos>0.7 element exceeds this
#define SELF_TERM 4.85165195e8f       // exp(20)

// ---------------- Kernel 1: row L2-normalize -> bf16 copy; zero accumulators --------
__global__ __launch_bounds__(256) void normalize_kernel(
    const float* __restrict__ feat, unsigned short* __restrict__ fb,
    float* __restrict__ hsum, float* __restrict__ nhighf,
    float* __restrict__ possum) {
    const int wave = threadIdx.x >> 6;
    const int lane = threadIdx.x & 63;
    const int row  = blockIdx.x * 4 + wave;
    float4 v = reinterpret_cast<const float4*>(feat + (size_t)row * ND)[lane];
    float ss = v.x * v.x + v.y * v.y + v.z * v.z + v.w * v.w;
    #pragma unroll
    for (int off = 32; off > 0; off >>= 1) ss += __shfl_xor(ss, off);
    const float inv = rsqrtf(ss);
    ushort4 o;
    __hip_bfloat16 h0 = __float2bfloat16(v.x * inv); o.x = *reinterpret_cast<unsigned short*>(&h0);
    __hip_bfloat16 h1 = __float2bfloat16(v.y * inv); o.y = *reinterpret_cast<unsigned short*>(&h1);
    __hip_bfloat16 h2 = __float2bfloat16(v.z * inv); o.z = *reinterpret_cast<unsigned short*>(&h2);
    __hip_bfloat16 h3 = __float2bfloat16(v.w * inv); o.w = *reinterpret_cast<unsigned short*>(&h3);
    reinterpret_cast<ushort4*>(fb + (size_t)row * ND)[lane] = o;
    // spare work: zero the cold-path accumulators + possum (sim runs after us)
    if (blockIdx.x < 32) {
        const int i = (blockIdx.x << 8) + threadIdx.x;
        hsum[i] = 0.f;
        nhighf[i] = 0.f;
    } else if (blockIdx.x == 32 && threadIdx.x == 0) {
        possum[0] = 0.f;
    }
}

// ---------------- Kernel 2: triangular sim tiles, LDS-staged ----------
// 2080 blocks = lower triangle (bi >= bj). Block: 4 waves, 128x128 tile; wave 64x64
// as 4x4 frags of v_mfma_f32_16x16x32_bf16. BK=64 LDS staging via global_load_lds
// width-16 with XOR-granule swizzle baked into the GLOBAL address.
// Row/col exp-sum partials -> Q (row slot [bi][bj], mirror col slot [bj][bi]),
// plain coalesced stores. Positive-pair cos sum accumulated in-register against
// LDS-staged labels -> ONE atomicAdd per block (replaces the 58 us classsum kernel).
__global__ __launch_bounds__(256, 3) void sim_kernel(
    const unsigned short* __restrict__ fb, const int* __restrict__ labels,
    float* __restrict__ Q, float* __restrict__ hsum,
    float* __restrict__ nhighf, float* __restrict__ possum) {
    __shared__ __align__(16) unsigned short ldsA[128 * BK];   // 16 KB
    __shared__ __align__(16) unsigned short ldsB[128 * BK];   // 16 KB
    __shared__ float ldsRow[2][128];
    __shared__ float ldsCol[2][128];
    __shared__ int   ldsLab[256];          // [0..127]=row labels, [128..255]=col labels
    __shared__ float ldsP[4];              // per-wave possum partials

    // triangular decode: t -> (bi, bj), bi >= bj
    const int t = blockIdx.x;
    int bi = (int)((sqrtf((float)(8 * t + 1)) - 1.0f) * 0.5f);
    while ((bi + 1) * (bi + 2) / 2 <= t) ++bi;
    while (bi * (bi + 1) / 2 > t) --bi;
    const int bj = t - bi * (bi + 1) / 2;
    const int I0 = bi << 7;
    const int J0 = bj << 7;
    const bool isdiag = (bi == bj);

    const int tid  = threadIdx.x;
    const int wave = tid >> 6;
    const int lane = tid & 63;
    const int wy = wave >> 1, wx = wave & 1;
    const int l15  = lane & 15;
    const int quad = lane >> 4;
    const bool dw = isdiag && (wy == wx);

    // stage the block's row+col labels (coalesced, once)
    if (tid < 128) ldsLab[tid] = labels[I0 + tid];
    else           ldsLab[tid] = labels[J0 + tid - 128];

    int offRC[4];
    #pragma unroll
    for (int c = 0; c < 4; ++c) {
        const int Lg = (c << 6) + lane;
        const int row_loc = (wave << 5) + (Lg >> 3);
        const int g = (Lg & 7) ^ ((Lg >> 3) & 7);
        offRC[c] = row_loc * ND + (g << 3);
    }
    const unsigned short* baseA = fb + (size_t)I0 * ND;
    const unsigned short* baseB = fb + (size_t)J0 * ND;

    f32x4 zero4 = {0.f, 0.f, 0.f, 0.f};
    f32x4 acc[4][4];
    #pragma unroll
    for (int fy = 0; fy < 4; ++fy)
        #pragma unroll
        for (int fx = 0; fx < 4; ++fx) acc[fy][fx] = zero4;

    for (int kk = 0; kk < ND; kk += BK) {
        __syncthreads();
        #pragma unroll
        for (int c = 0; c < 4; ++c) {
            __builtin_amdgcn_global_load_lds(
                (const __attribute__((address_space(1))) void*)(baseA + offRC[c] + kk),
                (__attribute__((address_space(3))) void*)(ldsA + (wave << 11) + (c << 9)),
                16, 0, 0);
            __builtin_amdgcn_global_load_lds(
                (const __attribute__((address_space(1))) void*)(baseB + offRC[c] + kk),
                (__attribute__((address_space(3))) void*)(ldsB + (wave << 11) + (c << 9)),
                16, 0, 0);
        }
        __syncthreads();

        #pragma unroll
        for (int s = 0; s < 2; ++s) {
            bf16x8 a[4], b[4];
            const int gsw = quad + (s << 2);
            #pragma unroll
            for (int f = 0; f < 4; ++f) {
                const int rowA = (wy << 6) + (f << 4) + l15;
                const int rowB = (wx << 6) + (f << 4) + l15;
                const int gp = gsw ^ (l15 & 7);
                a[f] = *reinterpret_cast<const bf16x8*>(ldsA + rowA * BK + (gp << 3));
                b[f] = *reinterpret_cast<const bf16x8*>(ldsB + rowB * BK + (gp << 3));
            }
            #pragma unroll
            for (int fy = 0; fy < 4; ++fy)
                #pragma unroll
                for (int fx = 0; fx < 4; ++fx)
                    acc[fy][fx] = __builtin_amdgcn_mfma_f32_16x16x32_bf16(
                        a[fy], b[fx], acc[fy][fx], 0, 0, 0);
        }
    }

    // Epilogue. C/D layout: col = l15, row = quad*4 + r (m89/m91-verified).
    const int rb = I0 + (wy << 6);
    const int cb = J0 + (wx << 6);
    int lcolr[4];
    #pragma unroll
    for (int fx = 0; fx < 4; ++fx) lcolr[fx] = ldsLab[128 + (wx << 6) + (fx << 4) + l15];

    int anyhigh = 0;
    float cs[4] = {0.f, 0.f, 0.f, 0.f};
    float pp = 0.f;                        // positive-pair cos partial
    #pragma unroll
    for (int fy = 0; fy < 4; ++fy) {
        #pragma unroll
        for (int r = 0; r < 4; ++r) {
            const bool isdiag_lane = dw && (l15 == (quad << 2) + r);
            const int lrow = ldsLab[(wy << 6) + (fy << 4) + (quad << 2) + r];
            float d = 0.f;
            #pragma unroll
            for (int fx = 0; fx < 4; ++fx) {
                const float a = acc[fy][fx][r];
                float e = exp2f(a * LOG2E_T);
                const bool diag_el = (fx == fy) && isdiag_lane;
                if (diag_el) e = 0.f;
                d += e;
                cs[fx] += e;
                if (lcolr[fx] == lrow && !diag_el) pp += a;
            }
            anyhigh |= (d > HI_THR);
            #pragma unroll
            for (int off = 8; off > 0; off >>= 1) d += __shfl_xor(d, off);
            if (l15 == 0)
                ldsRow[wx][(wy << 6) + (fy << 4) + (quad << 2) + r] = d;
        }
    }
    if (!isdiag) {
        #pragma unroll
        for (int fx = 0; fx < 4; ++fx) {
            cs[fx] += __shfl_xor(cs[fx], 16);
            cs[fx] += __shfl_xor(cs[fx], 32);
        }
        if (quad == 0) {
            #pragma unroll
            for (int fx = 0; fx < 4; ++fx)
                ldsCol[wy][(wx << 6) + (fx << 4) + l15] = cs[fx];
        }
    }
    // full-wave reduce of pp, stash per wave
    #pragma unroll
    for (int off = 32; off > 0; off >>= 1) pp += __shfl_xor(pp, off);
    if (lane == 0) ldsP[wave] = pp;

    __syncthreads();
    if (tid < 128) {
        Q[(size_t)(bi * 64 + bj) * 128 + tid] = ldsRow[0][tid] + ldsRow[1][tid];
    } else if (!isdiag) {
        const int c2 = tid - 128;
        Q[(size_t)(bj * 64 + bi) * 128 + c2] = ldsCol[0][c2] + ldsCol[1][c2];
    }
    if (tid == 0) {
        // off-diag tiles cover each unordered pair once -> mirror contributes 2x
        const float scale = isdiag ? 1.f : 2.f;
        const float tot = (ldsP[0] + ldsP[1] + ldsP[2] + ldsP[3]) * scale;
        atomicAdd(possum, tot);           // 2080 atomics total
    }

    // Cold path: some element had sim > 14 (cos > 0.7) -> relax-term bookkeeping.
    if (__any(anyhigh)) {
        float hc[4] = {0.f, 0.f, 0.f, 0.f}, nc[4] = {0.f, 0.f, 0.f, 0.f};
        #pragma unroll
        for (int fy = 0; fy < 4; ++fy) {
            #pragma unroll
            for (int r = 0; r < 4; ++r) {
                const int row  = rb + (fy << 4) + (quad << 2) + r;
                const int lrow = ldsLab[(wy << 6) + (fy << 4) + (quad << 2) + r];
                float hs = 0.f, nh = 0.f;
                #pragma unroll
                for (int fx = 0; fx < 4; ++fx) {
                    const int col = cb + (fx << 4) + l15;
                    const float a = acc[fy][fx][r];
                    if (a > 0.7f && lcolr[fx] == lrow && col != row) {
                        const float e = exp2f(a * LOG2E_T);
                        hs += e; nh += 1.f;
                        hc[fx] += e; nc[fx] += 1.f;
                    }
                }
                #pragma unroll
                for (int off = 8; off > 0; off >>= 1) {
                    hs += __shfl_xor(hs, off);
                    nh += __shfl_xor(nh, off);
                }
                if (l15 == 0 && nh > 0.f) {
                    atomicAdd(&hsum[row], hs);
                    atomicAdd(&nhighf[row], nh);
                }
            }
        }
        if (!isdiag) {
            #pragma unroll
            for (int fx = 0; fx < 4; ++fx) {
                hc[fx] += __shfl_xor(hc[fx], 16);
                hc[fx] += __shfl_xor(hc[fx], 32);
                nc[fx] += __shfl_xor(nc[fx], 16);
                nc[fx] += __shfl_xor(nc[fx], 32);
            }
            if (quad == 0) {
                #pragma unroll
                for (int fx = 0; fx < 4; ++fx) {
                    if (nc[fx] > 0.f) {
                        atomicAdd(&hsum[cb + (fx << 4) + l15], hc[fx]);
                        atomicAdd(&nhighf[cb + (fx << 4) + l15], nc[fx]);
                    }
                }
            }
        }
    }
}

// ---------------- Kernel 2b: fold Q partials into denom ----------------
__global__ __launch_bounds__(256) void reduce_kernel(
    const float* __restrict__ Q, float* __restrict__ denom) {
    const int g = blockIdx.x;
    const int t = threadIdx.x;
    const int r = t & 127;
    const int sh = t >> 7;
    const float* base = Q + (size_t)g * 64 * 128;
    float s = 0.f;
    #pragma unroll 8
    for (int i = 0; i < 32; ++i)
        s += base[(size_t)(sh * 32 + i) * 128 + r];
    __shared__ float red[256];
    red[t] = s;
    __syncthreads();
    if (t < 128) denom[g * 128 + t] = red[t] + red[t + 128];
}

// ---------------- Kernel 3: scalar finalize (w/ label histogram) ----------------
__global__ __launch_bounds__(256) void finalize_kernel(
    const float* __restrict__ denom, const float* __restrict__ hsum,
    const float* __restrict__ nhighf, const float* __restrict__ possum,
    const int* __restrict__ labels, float* __restrict__ out) {
    const int tid = threadIdx.x;
    __shared__ int cnt[128];
    if (tid < 128) cnt[tid] = 0;
    __syncthreads();
    for (int i = tid; i < NB; i += 256)
        atomicAdd(&cnt[labels[i]], 1);
    __syncthreads();
    float NT = 0.f;
    if (tid < NCLSR) {
        float nc = (float)cnt[tid];
        NT = nc * (nc - 1.f);
    }
    float SL = 0.f, RL = 0.f, NH = 0.f;
    for (int i = tid; i < NB; i += 256) {
        float np = (float)(cnt[labels[i]] - 1);
        SL += np * logf(denom[i] + 1e-8f);
        float h = hsum[i];
        if (h > 0.f) RL += logf(h + SELF_TERM);
        NH += nhighf[i];
    }
    #pragma unroll
    for (int off = 32; off > 0; off >>= 1) {
        NT += __shfl_xor(NT, off);
        SL += __shfl_xor(SL, off);
        RL += __shfl_xor(RL, off);
        NH += __shfl_xor(NH, off);
    }
    __shared__ float part[4][4];
    if ((tid & 63) == 0) {
        int w = tid >> 6;
        part[w][0] = NT; part[w][1] = SL; part[w][2] = RL; part[w][3] = NH;
    }
    __syncthreads();
    if (tid == 0) {
        float nt = part[0][0] + part[1][0] + part[2][0] + part[3][0];
        float sl = part[0][1] + part[1][1] + part[2][1] + part[3][1];
        float rl = part[0][2] + part[1][2] + part[2][2] + part[3][2];
        float nh = part[0][3] + part[1][3] + part[2][3] + part[3][3];
        float pos_sim = possum[0] * INV_T;     // sum of sim over ordered positive pairs
        float scl   = (nt > 0.f) ? (sl - pos_sim) / nt : 0.f;
        float relax = (nh > 0.f) ? rl / nh : 0.f;
        out[0] = scl + relax;
    }
}

extern "C" void kernel_launch(void* const* d_in, const int* in_sizes, int n_in,
                              void* d_out, int out_size, void* d_ws, size_t ws_size,
                              hipStream_t stream) {
    const float* feat  = (const float*)d_in[0];
    const int* labels  = (const int*)d_in[1];
    float* out = (float*)d_out;

    char* ws = (char*)d_ws;
    unsigned short* fb = (unsigned short*)ws;                              // 4 MB
    float* Q      = (float*)(ws + (size_t)NB * ND * sizeof(unsigned short)); // 2 MB
    float* denom  = Q + 64 * 64 * 128;
    float* hsum   = denom  + NB;
    float* nhighf = hsum   + NB;
    float* possum = nhighf + NB;          // 1 float

    normalize_kernel<<<NB / 4, 256, 0, stream>>>(feat, fb, hsum, nhighf, possum);
    sim_kernel<<<2080, 256, 0, stream>>>(fb, labels, Q, hsum, nhighf, possum);
    reduce_kernel<<<64, 256, 0, stream>>>(Q, denom);
    finalize_kernel<<<1, 256, 0, stream>>>(denom, hsum, nhighf, possum, labels, out);
}